// Round 1
// baseline (189.511 us; speedup 1.0000x reference)
//
#include <hip/hip_runtime.h>
#include <hip/hip_bf16.h>
#include <stdint.h>

// GAT: N=4096 nodes, F_in=512, H=8 heads, F_out=64.
// e_ij = lrelu(s_i + d_j); exp(lrelu(x)) factorizes into two rank-1 regimes:
//   x>0: e^{s_i} * e^{d_j}   ;   x<=0: e^{0.2 s_i} * e^{0.2 d_j}
// -> no per-pair exp, no online softmax (scores bounded ~|4|), adjacency as bitmask.

#define NN 4096
#define FIN 512
#define NH 8
#define FO 64

typedef __attribute__((ext_vector_type(8))) short bf16x8;
typedef __attribute__((ext_vector_type(4))) float f32x4;

__device__ __forceinline__ unsigned short f2bf(float f) {
  unsigned u = __float_as_uint(f);
  u += 0x7fffu + ((u >> 16) & 1u);   // RNE; inputs are finite
  return (unsigned short)(u >> 16);
}
__device__ __forceinline__ float bflo(unsigned w) { return __uint_as_float(w << 16); }
__device__ __forceinline__ float bfhi(unsigned w) { return __uint_as_float(w & 0xffff0000u); }

// ---------------- prep: adj->bits, X->bf16, W->WbT (bf16, [h][o][k]) ----------------
__global__ __launch_bounds__(256) void prep_kernel(
    const float* __restrict__ X, const int* __restrict__ adj, const float* __restrict__ W,
    unsigned short* __restrict__ Xb, unsigned short* __restrict__ WbT,
    unsigned* __restrict__ adjbits) {
  int bid = blockIdx.x, tid = threadIdx.x;
  if (bid < 2048) {                       // 4096*128 words, 1 word (32 adj entries)/thread
    int item = bid * 256 + tid;
    const int* p = adj + (size_t)(item >> 7) * NN + (item & 127) * 32;
    unsigned bits = 0;
#pragma unroll
    for (int b = 0; b < 32; b += 4) {
      int4 v = *(const int4*)(p + b);
      bits |= (v.x ? 1u : 0u) << b;
      bits |= (v.y ? 1u : 0u) << (b + 1);
      bits |= (v.z ? 1u : 0u) << (b + 2);
      bits |= (v.w ? 1u : 0u) << (b + 3);
    }
    adjbits[item] = bits;
  } else if (bid < 4096) {                // X -> bf16, float4/thread
    int item = (bid - 2048) * 256 + tid;
    float4 v = ((const float4*)X)[item];
    ushort4 o;
    o.x = f2bf(v.x); o.y = f2bf(v.y); o.z = f2bf(v.z); o.w = f2bf(v.w);
    ((ushort4*)Xb)[item] = o;
  } else {                                // W[h][k][o] -> WbT[h][o][k] bf16
    int item = (bid - 4096) * 256 + tid;
    int h = item >> 15, rem = item & 32767, o = rem >> 9, k = rem & 511;
    WbT[item] = f2bf(W[h * (FIN * FO) + k * FO + o]);
  }
}

// ---------------- proj: Wh = X @ W[h] (MFMA), epilogue s,d + exp tables + WhbT ------
// wave = 16 rows x 64 cols; D layout: col = lane&15, row = (lane>>4)*4 + reg  [m89]
__global__ __launch_bounds__(256) void proj_kernel(
    const unsigned short* __restrict__ Xb, const unsigned short* __restrict__ WbT,
    const float* __restrict__ a,
    unsigned short* __restrict__ WhbT, float4* __restrict__ ABT,
    unsigned* __restrict__ E12) {
  int h = blockIdx.y;
  int lane = threadIdx.x & 63, wave = threadIdx.x >> 6;
  int row16 = lane & 15, grp = lane >> 4;
  int i0 = blockIdx.x * 64 + wave * 16;
  f32x4 acc[4] = {{0,0,0,0},{0,0,0,0},{0,0,0,0},{0,0,0,0}};
  const unsigned short* xb = Xb + (size_t)(i0 + row16) * FIN + grp * 8;
  const unsigned short* wb = WbT + h * (FO * FIN) + row16 * FIN + grp * 8;
#pragma unroll 4
  for (int k0 = 0; k0 < FIN; k0 += 32) {
    bf16x8 af = *(const bf16x8*)(xb + k0);
#pragma unroll
    for (int cb = 0; cb < 4; ++cb) {
      bf16x8 bf = *(const bf16x8*)(wb + cb * 16 * FIN + k0);
      acc[cb] = __builtin_amdgcn_mfma_f32_16x16x32_bf16(af, bf, acc[cb], 0, 0, 0);
    }
  }
  // per-row dots with a1,a2: partial over this lane's 4 cols, reduce over 16 lanes
  float a1[4], a2[4];
#pragma unroll
  for (int cb = 0; cb < 4; ++cb) {
    a1[cb] = a[h * 128 + cb * 16 + row16];
    a2[cb] = a[h * 128 + 64 + cb * 16 + row16];
  }
  float sp[4] = {0,0,0,0}, dp[4] = {0,0,0,0};
#pragma unroll
  for (int reg = 0; reg < 4; ++reg)
#pragma unroll
    for (int cb = 0; cb < 4; ++cb) {
      sp[reg] += acc[cb][reg] * a1[cb];
      dp[reg] += acc[cb][reg] * a2[cb];
    }
#pragma unroll
  for (int m = 1; m <= 8; m <<= 1)
#pragma unroll
    for (int reg = 0; reg < 4; ++reg) {
      sp[reg] += __shfl_xor(sp[reg], m, 64);
      dp[reg] += __shfl_xor(dp[reg], m, 64);
    }
  // store WhbT[h][col][row] (transposed so flash B-frags are contiguous 16B)
#pragma unroll
  for (int cb = 0; cb < 4; ++cb) {
    ushort4 pk;
    pk.x = f2bf(acc[cb][0]); pk.y = f2bf(acc[cb][1]);
    pk.z = f2bf(acc[cb][2]); pk.w = f2bf(acc[cb][3]);
    *(ushort4*)(WhbT + (size_t)h * FO * NN + (size_t)(cb * 16 + row16) * NN + i0 + grp * 4) = pk;
  }
  if (row16 == 0) {
#pragma unroll
    for (int reg = 0; reg < 4; ++reg) {
      int r = i0 + grp * 4 + reg;
      float s = sp[reg], d = dp[reg];
      ABT[h * NN + r] = make_float4(__expf(s), __expf(0.2f * s), __expf(-s), 0.0f);
      unsigned e1 = f2bf(__expf(d));
      unsigned e2 = f2bf(__expf(0.2f * d));
      E12[h * NN + r] = e1 | (e2 << 16);
    }
  }
}

// ---------------- flash aggregation: out = softmax_adj(e) @ Wh --------------------
// wave = 16 rows (A-frag rows = lane&15), full 64 cols; 5th MFMA vs ones = denominator
__global__ __launch_bounds__(512) void gat_kernel(
    const unsigned* __restrict__ adjbits, const unsigned short* __restrict__ WhbT,
    const float4* __restrict__ ABT, const unsigned* __restrict__ E12,
    float* __restrict__ out) {
  int h = blockIdx.y;
  int lane = threadIdx.x & 63, wave = threadIdx.x >> 6;
  int row16 = lane & 15, grp = lane >> 4;
  int i0 = (blockIdx.x * 8 + wave) * 16;
  int r = i0 + row16;
  float4 abt = ABT[h * NN + r];
  float Ai = abt.x, Bi = abt.y, T = abt.z;

  f32x4 acc[4] = {{0,0,0,0},{0,0,0,0},{0,0,0,0},{0,0,0,0}};
  f32x4 accd = {0,0,0,0};
  bf16x8 ones;
#pragma unroll
  for (int e = 0; e < 8; ++e) ones[e] = (short)0x3F80;   // bf16 1.0

  const unsigned* bp = adjbits + (size_t)r * 128;
  const unsigned* ep = E12 + h * NN + grp * 8;
  const unsigned short* wp = WhbT + (size_t)h * FO * NN + (size_t)row16 * NN + grp * 8;

#pragma unroll 2
  for (int jt = 0; jt < 128; ++jt) {
    unsigned bword = bp[jt];
    unsigned bbyte = (bword >> (grp * 8)) & 0xffu;
    uint4 ea = *(const uint4*)(ep + jt * 32);
    uint4 eb = *(const uint4*)(ep + jt * 32 + 4);
    bf16x8 bf0 = *(const bf16x8*)(wp + 0 * 16 * NN + jt * 32);
    bf16x8 bf1 = *(const bf16x8*)(wp + 1 * 16 * NN + jt * 32);
    bf16x8 bf2 = *(const bf16x8*)(wp + 2 * 16 * NN + jt * 32);
    bf16x8 bf3 = *(const bf16x8*)(wp + 3 * 16 * NN + jt * 32);

    bf16x8 af;
#define MKP(e, w)                                                   \
    {                                                               \
      float E1 = bflo(w), E2 = bfhi(w);                             \
      float val = (E1 > T) ? (Ai * E1) : (Bi * E2);                 \
      val = (bbyte & (1u << (e))) ? val : 0.0f;                     \
      af[e] = (short)f2bf(val);                                     \
    }
    MKP(0, ea.x) MKP(1, ea.y) MKP(2, ea.z) MKP(3, ea.w)
    MKP(4, eb.x) MKP(5, eb.y) MKP(6, eb.z) MKP(7, eb.w)
#undef MKP

    acc[0] = __builtin_amdgcn_mfma_f32_16x16x32_bf16(af, bf0, acc[0], 0, 0, 0);
    acc[1] = __builtin_amdgcn_mfma_f32_16x16x32_bf16(af, bf1, acc[1], 0, 0, 0);
    acc[2] = __builtin_amdgcn_mfma_f32_16x16x32_bf16(af, bf2, acc[2], 0, 0, 0);
    acc[3] = __builtin_amdgcn_mfma_f32_16x16x32_bf16(af, ones, acc[3], 0, 0, 0);
    accd   = __builtin_amdgcn_mfma_f32_16x16x32_bf16(af, bf3, accd, 0, 0, 0);
    // NOTE: acc[3]<->accd roles: acc[3] holds cb=3 numerator? No — see below.
  }
  // Careful: above, acc[3] accumulated vs `ones` (denominator), accd vs bf3 (cb=3).
#pragma unroll
  for (int reg = 0; reg < 4; ++reg) {
    float inv = 1.0f / acc[3][reg];         // denominator for row i0+grp*4+reg
    int row = i0 + grp * 4 + reg;
    float* op = out + (size_t)row * (NH * FO) + h * FO + row16;
    op[0 * 16] = acc[0][reg] * inv;
    op[1 * 16] = acc[1][reg] * inv;
    op[2 * 16] = acc[2][reg] * inv;
    op[3 * 16] = accd[reg] * inv;
  }
}

extern "C" void kernel_launch(void* const* d_in, const int* in_sizes, int n_in,
                              void* d_out, int out_size, void* d_ws, size_t ws_size,
                              hipStream_t stream) {
  const float* X  = (const float*)d_in[0];
  const int* adj  = (const int*)d_in[1];
  const float* W  = (const float*)d_in[2];
  const float* a  = (const float*)d_in[3];
  float* out = (float*)d_out;
  char* ws = (char*)d_ws;

  unsigned short* Xb   = (unsigned short*)(ws + 0);          // 4 MB
  unsigned short* WbT  = (unsigned short*)(ws + 4194304);    // 512 KB
  unsigned* adjbits    = (unsigned*)(ws + 4718592);          // 2 MB
  unsigned short* WhbT = (unsigned short*)(ws + 6815744);    // 4 MB
  float4* ABT          = (float4*)(ws + 11010048);           // 512 KB
  unsigned* E12        = (unsigned*)(ws + 11534336);         // 128 KB  (total ~11.2 MB)

  prep_kernel<<<5120, 256, 0, stream>>>(X, adj, W, Xb, WbT, adjbits);
  proj_kernel<<<dim3(64, 8), 256, 0, stream>>>(Xb, WbT, a, WhbT, ABT, E12);
  gat_kernel<<<dim3(32, 8), 512, 0, stream>>>(adjbits, WhbT, ABT, E12, out);
}

// Round 2
// 113.357 us; speedup vs baseline: 1.6718x; 1.6718x over previous
//
#include <hip/hip_runtime.h>
#include <hip/hip_bf16.h>
#include <stdint.h>

// GAT: N=4096, F_in=512, H=8, F_out=64.
// exp(lrelu(s_i+d_j)) factorizes: pos -> e^{s_i}*e^{d_j}, neg -> e^{0.2 s_i}*e^{0.2 d_j}
// -> no per-pair exp, no online softmax (scores bounded), adjacency as bitmask.
// Round 2: 2-way j-split (occupancy), depth-1 prefetch, fragment-order Wh layout,
// transposed adj bits, f32 E-tables.

#define NN 4096
#define FIN 512
#define NH 8
#define FO 64

typedef __attribute__((ext_vector_type(8))) short bf16x8;
typedef __attribute__((ext_vector_type(4))) float f32x4;

__device__ __forceinline__ unsigned short f2bf(float f) {
  unsigned u = __float_as_uint(f);
  u += 0x7fffu + ((u >> 16) & 1u);   // RNE; finite inputs
  return (unsigned short)(u >> 16);
}

// ---------------- prep: adj->bitsT, X->bf16, W->WbT ----------------
__global__ __launch_bounds__(256) void prep_kernel(
    const float* __restrict__ X, const int* __restrict__ adj, const float* __restrict__ W,
    unsigned short* __restrict__ Xb, unsigned short* __restrict__ WbT,
    unsigned* __restrict__ adjbitsT) {
  int bid = blockIdx.x, tid = threadIdx.x;
  if (bid < 2048) {                       // adj -> bit words, transposed [jt][r]
    int item = bid * 256 + tid;           // item = jt*4096 + r
    int jt = item >> 12, r = item & 4095;
    const int* p = adj + (size_t)r * NN + jt * 32;
    unsigned bits = 0;
#pragma unroll
    for (int b = 0; b < 32; b += 4) {
      int4 v = *(const int4*)(p + b);
      bits |= (unsigned)(v.x & 1) << b;
      bits |= (unsigned)(v.y & 1) << (b + 1);
      bits |= (unsigned)(v.z & 1) << (b + 2);
      bits |= (unsigned)(v.w & 1) << (b + 3);
    }
    adjbitsT[item] = bits;                // coalesced write
  } else if (bid < 4096) {                // X -> bf16
    int item = (bid - 2048) * 256 + tid;
    float4 v = ((const float4*)X)[item];
    ushort4 o;
    o.x = f2bf(v.x); o.y = f2bf(v.y); o.z = f2bf(v.z); o.w = f2bf(v.w);
    ((ushort4*)Xb)[item] = o;
  } else {                                // W[h][k][o] -> WbT[h][o][k]
    int item = (bid - 4096) * 256 + tid;
    int h = item >> 15, rem = item & 32767, o = rem >> 9, k = rem & 511;
    WbT[item] = f2bf(W[h * (FIN * FO) + k * FO + o]);
  }
}

// ---------------- proj: Wh = X @ W[h]; epilogue -> Whfrag, exp tables ------------
// D layout (16x16x32): col = lane&15, row = (lane>>4)*4 + reg   [m89]
__global__ __launch_bounds__(256) void proj_kernel(
    const unsigned short* __restrict__ Xb, const unsigned short* __restrict__ WbT,
    const float* __restrict__ a,
    unsigned short* __restrict__ Whfrag, float4* __restrict__ ABT,
    float* __restrict__ E1f, float* __restrict__ E2f) {
  int h = blockIdx.y;
  int lane = threadIdx.x & 63, wave = threadIdx.x >> 6;
  int row16 = lane & 15, grp = lane >> 4;
  int i0 = blockIdx.x * 64 + wave * 16;
  f32x4 acc[4] = {{0,0,0,0},{0,0,0,0},{0,0,0,0},{0,0,0,0}};
  const unsigned short* xb = Xb + (size_t)(i0 + row16) * FIN + grp * 8;
  const unsigned short* wb = WbT + h * (FO * FIN) + row16 * FIN + grp * 8;
#pragma unroll 4
  for (int k0 = 0; k0 < FIN; k0 += 32) {
    bf16x8 af = *(const bf16x8*)(xb + k0);
#pragma unroll
    for (int cb = 0; cb < 4; ++cb) {
      bf16x8 bf = *(const bf16x8*)(wb + cb * 16 * FIN + k0);
      acc[cb] = __builtin_amdgcn_mfma_f32_16x16x32_bf16(af, bf, acc[cb], 0, 0, 0);
    }
  }
  // s,d per row: partial over this lane's 4 cols, reduce over the 16 col-lanes
  float a1[4], a2[4];
#pragma unroll
  for (int cb = 0; cb < 4; ++cb) {
    a1[cb] = a[h * 128 + cb * 16 + row16];
    a2[cb] = a[h * 128 + 64 + cb * 16 + row16];
  }
  float sp[4] = {0,0,0,0}, dp[4] = {0,0,0,0};
#pragma unroll
  for (int reg = 0; reg < 4; ++reg)
#pragma unroll
    for (int cb = 0; cb < 4; ++cb) {
      sp[reg] += acc[cb][reg] * a1[cb];
      dp[reg] += acc[cb][reg] * a2[cb];
    }
#pragma unroll
  for (int m = 1; m <= 8; m <<= 1)
#pragma unroll
    for (int reg = 0; reg < 4; ++reg) {
      sp[reg] += __shfl_xor(sp[reg], m, 64);
      dp[reg] += __shfl_xor(dp[reg], m, 64);
    }
  // Whfrag[h][jt][cb][l][e] = Wh[jt*32 + (l>>4)*8 + e][cb*16 + (l&15)]  (flash B-frag order)
  {
    int jt = i0 >> 5;
    int kk0 = (i0 & 31) + grp * 4;        // = (wave&1)*16 + grp*4
    int tl = (kk0 >> 3) * 16 + row16;     // target lane
    int e0 = kk0 & 7;                     // 0 or 4
#pragma unroll
    for (int cb = 0; cb < 4; ++cb) {
      ushort4 pk;
      pk.x = f2bf(acc[cb][0]); pk.y = f2bf(acc[cb][1]);
      pk.z = f2bf(acc[cb][2]); pk.w = f2bf(acc[cb][3]);
      *(ushort4*)(Whfrag + (((size_t)h * 128 + jt) * 4 + cb) * 512 + tl * 8 + e0) = pk;
    }
  }
  if (row16 == 0) {
#pragma unroll
    for (int reg = 0; reg < 4; ++reg) {
      int r = i0 + grp * 4 + reg;
      float s = sp[reg], d = dp[reg];
      ABT[h * NN + r] = make_float4(__expf(s), __expf(0.2f * s), __expf(-s), 0.0f);
      E1f[h * NN + r] = __expf(d);
      E2f[h * NN + r] = __expf(0.2f * d);
    }
  }
}

// ---------------- flash aggregation with 2-way j-split --------------------
struct Frag {
  unsigned bw;
  float4 e1a, e1b, e2a, e2b;
  bf16x8 b0, b1, b2, b3;
};

__device__ __forceinline__ Frag ld_frag(const unsigned* __restrict__ bpT,
                                        const float* __restrict__ e1p,
                                        const float* __restrict__ e2p,
                                        const unsigned short* __restrict__ wfp, int jt) {
  Frag f;
  f.bw  = bpT[(size_t)jt * NN];
  f.e1a = *(const float4*)(e1p + jt * 32);
  f.e1b = *(const float4*)(e1p + jt * 32 + 4);
  f.e2a = *(const float4*)(e2p + jt * 32);
  f.e2b = *(const float4*)(e2p + jt * 32 + 4);
  const unsigned short* w = wfp + (size_t)jt * 2048;
  f.b0 = *(const bf16x8*)(w);
  f.b1 = *(const bf16x8*)(w + 512);
  f.b2 = *(const bf16x8*)(w + 1024);
  f.b3 = *(const bf16x8*)(w + 1536);
  return f;
}

__device__ __forceinline__ void gat_body(const Frag& f, int grp, float Ai, float Bi, float T,
                                         const bf16x8& ones, f32x4& a0, f32x4& a1, f32x4& a2,
                                         f32x4& a3, f32x4& ad) {
  unsigned bb = (f.bw >> (grp * 8)) & 0xffu;
  float E1[8] = {f.e1a.x, f.e1a.y, f.e1a.z, f.e1a.w, f.e1b.x, f.e1b.y, f.e1b.z, f.e1b.w};
  float E2[8] = {f.e2a.x, f.e2a.y, f.e2a.z, f.e2a.w, f.e2b.x, f.e2b.y, f.e2b.z, f.e2b.w};
  bf16x8 af;
#pragma unroll
  for (int e = 0; e < 8; ++e) {
    bool pos = E1[e] > T;
    float sE = pos ? E1[e] : E2[e];
    float sAB = pos ? Ai : Bi;
    sAB = (bb & (1u << e)) ? sAB : 0.0f;
    float val = sE * sAB;
    __hip_bfloat16 hb = __float2bfloat16(val);
    af[e] = *reinterpret_cast<short*>(&hb);
  }
  a0 = __builtin_amdgcn_mfma_f32_16x16x32_bf16(af, f.b0, a0, 0, 0, 0);
  a1 = __builtin_amdgcn_mfma_f32_16x16x32_bf16(af, f.b1, a1, 0, 0, 0);
  a2 = __builtin_amdgcn_mfma_f32_16x16x32_bf16(af, f.b2, a2, 0, 0, 0);
  a3 = __builtin_amdgcn_mfma_f32_16x16x32_bf16(af, ones, a3, 0, 0, 0);  // denominator
  ad = __builtin_amdgcn_mfma_f32_16x16x32_bf16(af, f.b3, ad, 0, 0, 0);
}

__global__ __launch_bounds__(512, 4) void gat_kernel(
    const unsigned* __restrict__ adjbitsT, const unsigned short* __restrict__ Whfrag,
    const float4* __restrict__ ABT, const float* __restrict__ E1f,
    const float* __restrict__ E2f,
    float* __restrict__ N0, float* __restrict__ outbuf, float* __restrict__ Dd) {
  int h = blockIdx.y, z = blockIdx.z;
  int lane = threadIdx.x & 63, wave = threadIdx.x >> 6;
  int row16 = lane & 15, grp = lane >> 4;
  int i0 = (blockIdx.x * 8 + wave) * 16;
  int r = i0 + row16;
  float4 abt = ABT[h * NN + r];
  float Ai = abt.x, Bi = abt.y, T = abt.z;

  bf16x8 ones;
#pragma unroll
  for (int e = 0; e < 8; ++e) ones[e] = (short)0x3F80;

  const unsigned* bpT = adjbitsT + r;
  const float* e1p = E1f + h * NN + grp * 8;
  const float* e2p = E2f + h * NN + grp * 8;
  const unsigned short* wfp = Whfrag + (size_t)h * 128 * 2048 + lane * 8;

  f32x4 a0 = {0,0,0,0}, a1 = {0,0,0,0}, a2 = {0,0,0,0}, a3 = {0,0,0,0}, ad = {0,0,0,0};
  int jt0 = z * 64;
  Frag cur = ld_frag(bpT, e1p, e2p, wfp, jt0);
#pragma unroll 2
  for (int t = 1; t < 64; ++t) {
    Frag nxt = ld_frag(bpT, e1p, e2p, wfp, jt0 + t);   // prefetch next tile
    gat_body(cur, grp, Ai, Bi, T, ones, a0, a1, a2, a3, ad);
    cur = nxt;
  }
  gat_body(cur, grp, Ai, Bi, T, ones, a0, a1, a2, a3, ad);

  float* base;
  int rs;
  if (z == 0) { base = N0 + (size_t)h * NN * FO; rs = FO; }
  else        { base = outbuf + h * FO;          rs = NH * FO; }
#pragma unroll
  for (int reg = 0; reg < 4; ++reg) {
    int row = i0 + grp * 4 + reg;
    float* op = base + (size_t)row * rs + row16;
    op[0]  = a0[reg];
    op[16] = a1[reg];
    op[32] = a2[reg];
    op[48] = ad[reg];
  }
  if (row16 == 0) {
#pragma unroll
    for (int reg = 0; reg < 4; ++reg)
      Dd[((size_t)z * NH + h) * NN + i0 + grp * 4 + reg] = a3[reg];
  }
}

// ---------------- reduce + normalize --------------------
__global__ __launch_bounds__(256) void norm_kernel(
    const float* __restrict__ N0, const float* __restrict__ Dd, float* __restrict__ out) {
  int idx = (blockIdx.x * 256 + threadIdx.x) * 4;      // over 4096*512 f32
  int r = idx >> 9, c = idx & 511, h = c >> 6, o = c & 63;
  float4 n1 = *(const float4*)(out + idx);
  float4 n0 = *(const float4*)(N0 + ((size_t)h * NN + r) * FO + o);
  float inv = 1.0f / (Dd[h * NN + r] + Dd[(NH + h) * NN + r]);
  float4 res;
  res.x = (n1.x + n0.x) * inv;
  res.y = (n1.y + n0.y) * inv;
  res.z = (n1.z + n0.z) * inv;
  res.w = (n1.w + n0.w) * inv;
  *(float4*)(out + idx) = res;
}

extern "C" void kernel_launch(void* const* d_in, const int* in_sizes, int n_in,
                              void* d_out, int out_size, void* d_ws, size_t ws_size,
                              hipStream_t stream) {
  const float* X  = (const float*)d_in[0];
  const int* adj  = (const int*)d_in[1];
  const float* W  = (const float*)d_in[2];
  const float* a  = (const float*)d_in[3];
  float* out = (float*)d_out;
  char* ws = (char*)d_ws;

  unsigned short* Xb     = (unsigned short*)(ws + 0);          // 4 MB
  unsigned short* WbT    = (unsigned short*)(ws + 4194304);    // 512 KB
  unsigned* adjbitsT     = (unsigned*)(ws + 4718592);          // 2 MB
  unsigned short* Whfrag = (unsigned short*)(ws + 6815744);    // 4 MB
  float4* ABT            = (float4*)(ws + 11010048);           // 512 KB
  float* E1f             = (float*)(ws + 11534336);            // 128 KB
  float* E2f             = (float*)(ws + 11665408);            // 128 KB
  float* N0              = (float*)(ws + 11796480);            // 8 MB
  float* Dd              = (float*)(ws + 20185088);            // 256 KB (total ~19.5 MB)

  prep_kernel<<<5120, 256, 0, stream>>>(X, adj, W, Xb, WbT, adjbitsT);
  proj_kernel<<<dim3(64, 8), 256, 0, stream>>>(Xb, WbT, a, Whfrag, ABT, E1f, E2f);
  gat_kernel<<<dim3(32, 8, 2), 512, 0, stream>>>(adjbitsT, Whfrag, ABT, E1f, E2f, N0, out, Dd);
  norm_kernel<<<2048, 256, 0, stream>>>(N0, Dd, out);
}